// Round 1
// baseline (748.905 us; speedup 1.0000x reference)
//
#include <hip/hip_runtime.h>
#include <math.h>

// Problem constants (from reference)
#define BB 32
#define HH 512
#define WW 512
#define T_STEPS 16
#define DT_C 0.2f
#define HW (HH * WW)   // 262144 elements per sample (C=1)

// Block-level sum of 256 threads' values (4 waves of 64).
__device__ __forceinline__ float block_sum_256(float v) {
    __shared__ float lds[4];
#pragma unroll
    for (int off = 32; off > 0; off >>= 1)
        v += __shfl_down(v, off, 64);
    const int lane = threadIdx.x & 63;
    const int wid  = threadIdx.x >> 6;
    if (lane == 0) lds[wid] = v;
    __syncthreads();
    float s = 0.f;
    if (threadIdx.x == 0) s = lds[0] + lds[1] + lds[2] + lds[3];
    return s;
}

// Initial per-sample sum of x (only needed for samples with t > 0).
// grid: (64, 32), block: 256. Each thread sums 4 float4 = 16 elems.
__global__ __launch_bounds__(256) void reduce_x_kernel(
        const float* __restrict__ x, const int* __restrict__ t,
        float* __restrict__ sums) {
    const int b = blockIdx.y;
    if (t[b] <= 0) return;
    const float4* xb = (const float4*)(x + (size_t)b * HW);
    // 64 blocks * 256 threads * 4 float4 = 65536 float4 = HW/4
    float v = 0.f;
    int base = (blockIdx.x * 256 + threadIdx.x) * 4;
#pragma unroll
    for (int k = 0; k < 4; k++) {
        float4 c = xb[base + k];
        v += (c.x + c.y) + (c.z + c.w);
    }
    float s = block_sum_256(v);
    if (threadIdx.x == 0) atomicAdd(&sums[b], s);
}

// One Euler step for all samples still active at `step`; also handles the
// one-time copy-to-out for samples that just finished with odd t (or t==0).
// grid: (256, 32), block: 256. Each thread owns one float4 (4 elems).
__global__ __launch_bounds__(256) void step_kernel(
        const float* __restrict__ src,   // field read by this step
        float* __restrict__ dst,         // field written by this step
        const float* __restrict__ x,     // original input (copy path, t==0)
        const float* __restrict__ fld,   // ws field (copy path, odd t)
        float* __restrict__ out,         // final output (copy destination)
        const int* __restrict__ t,
        const float* __restrict__ dcoef,
        float* __restrict__ sums,        // [T_STEPS+1][BB]
        int step) {
    const int b = blockIdx.y;
    const int tb = t[b];

    if (step < tb) {
        // ---- active diffusion step ----
        const float mean = sums[step * BB + b] * (1.0f / (float)HW);
        const float D = dcoef[0] / (1.0f + expf(-mean));
        const float f = D * DT_C;

        const float* sb = src + (size_t)b * HW;
        float* db = dst + (size_t)b * HW;

        const int flat4 = blockIdx.x * 256 + threadIdx.x;   // 0..65535
        const int h  = flat4 >> 7;            // 512/4 = 128 float4 per row
        const int w  = (flat4 & 127) << 2;
        const int hm = (h + HH - 1) & (HH - 1);
        const int hp = (h + 1) & (HH - 1);

        const float4 c  = *(const float4*)(sb + h  * WW + w);
        const float4 up = *(const float4*)(sb + hm * WW + w);
        const float4 dn = *(const float4*)(sb + hp * WW + w);
        const float left  = sb[h * WW + ((w + WW - 1) & (WW - 1))];
        const float right = sb[h * WW + ((w + 4) & (WW - 1))];

        float4 o;
        o.x = c.x + f * (left + c.y + up.x + dn.x - 4.f * c.x);
        o.y = c.y + f * (c.x  + c.z + up.y + dn.y - 4.f * c.y);
        o.z = c.z + f * (c.y  + c.w + up.z + dn.z - 4.f * c.z);
        o.w = c.w + f * (c.z  + right + up.w + dn.w - 4.f * c.w);
        o.x = fminf(fmaxf(o.x, 0.f), 1.f);
        o.y = fminf(fmaxf(o.y, 0.f), 1.f);
        o.z = fminf(fmaxf(o.z, 0.f), 1.f);
        o.w = fminf(fmaxf(o.w, 0.f), 1.f);
        *(float4*)(db + h * WW + w) = o;

        if (step + 1 < tb) {   // block-uniform branch
            float s = block_sum_256((o.x + o.y) + (o.z + o.w));
            if (threadIdx.x == 0)
                atomicAdd(&sums[(step + 1) * BB + b], s);
        }
    } else if (step == tb && (tb == 0 || (tb & 1))) {
        // ---- sample just finished; final data is not in `out` yet ----
        // t==0: data is x. t odd: last write was step t-1 (even) -> ws field.
        const float* cs = (tb == 0) ? x : fld;
        const float4* s4 = (const float4*)(cs + (size_t)b * HW);
        float4* d4 = (float4*)(out + (size_t)b * HW);
        const int flat4 = blockIdx.x * 256 + threadIdx.x;
        float4 v = s4[flat4];
        v.x = fminf(fmaxf(v.x, 0.f), 1.f);
        v.y = fminf(fmaxf(v.y, 0.f), 1.f);
        v.z = fminf(fmaxf(v.z, 0.f), 1.f);
        v.w = fminf(fmaxf(v.w, 0.f), 1.f);
        d4[flat4] = v;
    }
    // else: sample finished earlier; its data already sits in `out`. No-op.
}

extern "C" void kernel_launch(void* const* d_in, const int* in_sizes, int n_in,
                              void* d_out, int out_size, void* d_ws, size_t ws_size,
                              hipStream_t stream) {
    const float* x     = (const float*)d_in[0];
    const int*   t     = (const int*)d_in[1];
    const float* dcoef = (const float*)d_in[2];
    float* out = (float*)d_out;

    // ws layout: [sums: (T_STEPS+1)*BB floats, padded to 4 KiB][field: 32 MiB]
    float* sums  = (float*)d_ws;
    float* field = (float*)((char*)d_ws + 4096);

    // Zero the step sums (ws is poisoned once and never restored by harness).
    hipMemsetAsync(sums, 0, sizeof(float) * BB * (T_STEPS + 1), stream);

    dim3 blk(256);
    reduce_x_kernel<<<dim3(64, BB), blk, 0, stream>>>(x, t, sums);

    for (int i = 0; i < T_STEPS; i++) {
        const float* src = (i == 0) ? x : ((i & 1) ? field : out);
        float* dst = (i & 1) ? out : field;
        step_kernel<<<dim3(256, BB), blk, 0, stream>>>(
            src, dst, x, field, out, t, dcoef, sums, i);
    }
}

// Round 2
// 259.063 us; speedup vs baseline: 2.8908x; 2.8908x over previous
//
#include <hip/hip_runtime.h>
#include <math.h>

// Problem constants (from reference)
#define BB 32
#define HH 512
#define WW 512
#define T_STEPS 16
#define DT_C 0.2f
#define HW (HH * WW)   // 262144 elements per sample (C=1)

// ---------------------------------------------------------------------------
// Key math fact: with periodic BC the 5-point Laplacian is mean-zero, and
// since f = d_coef * sigmoid(mean) * DT < 0.25, the update
//   y_new = y*(1-4f) + f*sum(neighbors)
// is a convex-ish combination keeping y in [0,1] -> clip never fires and the
// per-sample mean is invariant. So D = d_coef * sigmoid(mean(x)) is CONSTANT
// across all steps: no per-step reduction / atomics / barriers needed.
// ---------------------------------------------------------------------------

// Initial per-sample sum of x. grid: (64, 32), block: 256.
__global__ __launch_bounds__(256) void reduce_x_kernel(
        const float* __restrict__ x, const int* __restrict__ t,
        float* __restrict__ sums) {
    const int b = blockIdx.y;
    if (t[b] <= 0) return;                 // D unused for t==0 samples
    const float4* xb = (const float4*)(x + (size_t)b * HW);
    float v = 0.f;
    int base = (blockIdx.x * 256 + threadIdx.x) * 4;
#pragma unroll
    for (int k = 0; k < 4; k++) {
        float4 c = xb[base + k];
        v += (c.x + c.y) + (c.z + c.w);
    }
    // wave reduce (64-wide) then one atomic per wave (64 per address total)
#pragma unroll
    for (int off = 32; off > 0; off >>= 1)
        v += __shfl_down(v, off, 64);
    if ((threadIdx.x & 63) == 0) atomicAdd(&sums[b], v);
}

// Tiny kernel: f[b] = d_coef * sigmoid(mean) * DT, once per launch.
__global__ void factor_kernel(const float* __restrict__ sums,
                              const float* __restrict__ dcoef,
                              float* __restrict__ f) {
    const int b = threadIdx.x;
    if (b < BB) {
        const float mean = sums[b] * (1.0f / (float)HW);
        f[b] = dcoef[0] * (1.0f / (1.0f + expf(-mean))) * DT_C;
    }
}

// One Euler step for all samples still active at `step`; also handles the
// one-time copy-to-out for samples that finish with odd t (or t==0).
// grid: (256, 32), block: 256. Each thread owns one float4 (4 elems).
__global__ __launch_bounds__(256) void step_kernel(
        const float* __restrict__ src,   // field read by this step
        float* __restrict__ dst,         // field written by this step
        const float* __restrict__ x,     // original input (copy path, t==0)
        const float* __restrict__ fld,   // ws field (copy path, odd t)
        float* __restrict__ out,         // final output (copy destination)
        const int* __restrict__ t,
        const float* __restrict__ fvec,  // [BB] precomputed D*DT
        int step) {
    const int b = blockIdx.y;
    const int tb = t[b];

    if (step < tb) {
        // ---- active diffusion step: pure streaming stencil ----
        const float f = fvec[b];

        const float* sb = src + (size_t)b * HW;
        float* db = dst + (size_t)b * HW;

        const int flat4 = blockIdx.x * 256 + threadIdx.x;   // 0..65535
        const int h  = flat4 >> 7;            // 512/4 = 128 float4 per row
        const int w  = (flat4 & 127) << 2;
        const int hm = (h + HH - 1) & (HH - 1);
        const int hp = (h + 1) & (HH - 1);

        const float4 c  = *(const float4*)(sb + h  * WW + w);
        const float4 up = *(const float4*)(sb + hm * WW + w);
        const float4 dn = *(const float4*)(sb + hp * WW + w);
        const float left  = sb[h * WW + ((w + WW - 1) & (WW - 1))];
        const float right = sb[h * WW + ((w + 4) & (WW - 1))];

        float4 o;
        o.x = c.x + f * (left + c.y + up.x + dn.x - 4.f * c.x);
        o.y = c.y + f * (c.x  + c.z + up.y + dn.y - 4.f * c.y);
        o.z = c.z + f * (c.y  + c.w + up.z + dn.z - 4.f * c.z);
        o.w = c.w + f * (c.z  + right + up.w + dn.w - 4.f * c.w);
        o.x = fminf(fmaxf(o.x, 0.f), 1.f);
        o.y = fminf(fmaxf(o.y, 0.f), 1.f);
        o.z = fminf(fmaxf(o.z, 0.f), 1.f);
        o.w = fminf(fmaxf(o.w, 0.f), 1.f);
        *(float4*)(db + h * WW + w) = o;
    } else if (step == tb && (tb == 0 || (tb & 1))) {
        // ---- sample just finished; final data is not in `out` yet ----
        // t==0: data is x. t odd: last write was step t-1 (even) -> ws field.
        const float* cs = (tb == 0) ? x : fld;
        const float4* s4 = (const float4*)(cs + (size_t)b * HW);
        float4* d4 = (float4*)(out + (size_t)b * HW);
        const int flat4 = blockIdx.x * 256 + threadIdx.x;
        float4 v = s4[flat4];
        v.x = fminf(fmaxf(v.x, 0.f), 1.f);
        v.y = fminf(fmaxf(v.y, 0.f), 1.f);
        v.z = fminf(fmaxf(v.z, 0.f), 1.f);
        v.w = fminf(fmaxf(v.w, 0.f), 1.f);
        d4[flat4] = v;
    }
    // else: sample finished earlier; its data already sits in `out`. No-op.
}

extern "C" void kernel_launch(void* const* d_in, const int* in_sizes, int n_in,
                              void* d_out, int out_size, void* d_ws, size_t ws_size,
                              hipStream_t stream) {
    const float* x     = (const float*)d_in[0];
    const int*   t     = (const int*)d_in[1];
    const float* dcoef = (const float*)d_in[2];
    float* out = (float*)d_out;

    // ws layout: [sums: BB floats][f: BB floats] ... [field @ 4 KiB: 32 MiB]
    float* sums  = (float*)d_ws;
    float* fvec  = sums + BB;
    float* field = (float*)((char*)d_ws + 4096);

    hipMemsetAsync(sums, 0, sizeof(float) * BB, stream);

    dim3 blk(256);
    reduce_x_kernel<<<dim3(64, BB), blk, 0, stream>>>(x, t, sums);
    factor_kernel<<<1, 64, 0, stream>>>(sums, dcoef, fvec);

    for (int i = 0; i < T_STEPS; i++) {
        const float* src = (i == 0) ? x : ((i & 1) ? field : out);
        float* dst = (i & 1) ? out : field;
        step_kernel<<<dim3(256, BB), blk, 0, stream>>>(
            src, dst, x, field, out, t, fvec, i);
    }
}

// Round 3
// 182.795 us; speedup vs baseline: 4.0970x; 1.4172x over previous
//
#include <hip/hip_runtime.h>
#include <math.h>

// Problem constants (from reference)
#define BB 32
#define HH 512
#define WW 512
#define T_STEPS 16
#define DT_C 0.2f
#define HW (HH * WW)        // 262144 elements per sample (C=1)
#define RBLK 16             // reduce blocks per sample (partials = 16*32*4B = 2KB)

// ---------------------------------------------------------------------------
// Math fact (round 1): periodic Laplacian is mean-zero and f < 0.25 keeps
// y in [0,1] (clip never fires), so the per-sample mean is invariant and
// D = d_coef * sigmoid(mean(x)) is CONSTANT across steps. One reduction of x
// up front; every step is a pure streaming stencil.
// Round 2 lesson: 256 same-address atomics serialized 75us -> two-stage
// deterministic reduction with plain stores, no atomics anywhere.
// ---------------------------------------------------------------------------

__device__ __forceinline__ float block_sum_256(float v) {
    __shared__ float lds[4];
#pragma unroll
    for (int off = 32; off > 0; off >>= 1)
        v += __shfl_down(v, off, 64);
    const int lane = threadIdx.x & 63;
    const int wid  = threadIdx.x >> 6;
    if (lane == 0) lds[wid] = v;
    __syncthreads();
    float s = 0.f;
    if (threadIdx.x == 0) s = lds[0] + lds[1] + lds[2] + lds[3];
    return s;
}

// Stage 1: per-block partial sums of x. grid: (RBLK, BB), block: 256.
// Each thread sums 16 float4 (64 elems); one plain store per block.
__global__ __launch_bounds__(256) void reduce_x_kernel(
        const float* __restrict__ x, const int* __restrict__ t,
        float* __restrict__ partials) {
    const int b = blockIdx.y;
    if (t[b] <= 0) return;                 // D unused for t==0 samples
    const float4* xb = (const float4*)(x + (size_t)b * HW);
    float v = 0.f;
    const int base = blockIdx.x * (HW / 4 / RBLK);   // 4096 float4 per block
#pragma unroll
    for (int k = 0; k < 16; k++) {
        float4 c = xb[base + k * 256 + threadIdx.x];
        v += (c.x + c.y) + (c.z + c.w);
    }
    float s = block_sum_256(v);
    if (threadIdx.x == 0) partials[b * RBLK + blockIdx.x] = s;
}

// Stage 2: f[b] = d_coef * sigmoid(mean) * DT. grid: (BB), block: 64.
__global__ void factor_kernel(const float* __restrict__ partials,
                              const int* __restrict__ t,
                              const float* __restrict__ dcoef,
                              float* __restrict__ f) {
    const int b = blockIdx.x;
    float v = (threadIdx.x < RBLK && t[b] > 0)
                  ? partials[b * RBLK + threadIdx.x] : 0.f;
#pragma unroll
    for (int off = 8; off > 0; off >>= 1)
        v += __shfl_down(v, off, 64);
    if (threadIdx.x == 0) {
        const float mean = v * (1.0f / (float)HW);
        f[b] = dcoef[0] * (1.0f / (1.0f + expf(-mean))) * DT_C;
    }
}

// One Euler step for all samples still active at `step`; also handles the
// one-time copy-to-out for samples that finish with odd t (or t==0).
// grid: (256, BB), block: 256. Each thread owns one float4 (4 elems).
__global__ __launch_bounds__(256) void step_kernel(
        const float* __restrict__ src,   // field read by this step
        float* __restrict__ dst,         // field written by this step
        const float* __restrict__ x,     // original input (copy path, t==0)
        const float* __restrict__ fld,   // ws field (copy path, odd t)
        float* __restrict__ out,         // final output (copy destination)
        const int* __restrict__ t,
        const float* __restrict__ fvec,  // [BB] precomputed D*DT
        int step) {
    const int b = blockIdx.y;
    const int tb = t[b];

    if (step < tb) {
        // ---- active diffusion step: pure streaming stencil ----
        const float f = fvec[b];

        const float* sb = src + (size_t)b * HW;
        float* db = dst + (size_t)b * HW;

        const int flat4 = blockIdx.x * 256 + threadIdx.x;   // 0..65535
        const int h  = flat4 >> 7;            // 512/4 = 128 float4 per row
        const int w  = (flat4 & 127) << 2;
        const int hm = (h + HH - 1) & (HH - 1);
        const int hp = (h + 1) & (HH - 1);

        const float4 c  = *(const float4*)(sb + h  * WW + w);
        const float4 up = *(const float4*)(sb + hm * WW + w);
        const float4 dn = *(const float4*)(sb + hp * WW + w);
        const float left  = sb[h * WW + ((w + WW - 1) & (WW - 1))];
        const float right = sb[h * WW + ((w + 4) & (WW - 1))];

        float4 o;
        o.x = c.x + f * (left + c.y + up.x + dn.x - 4.f * c.x);
        o.y = c.y + f * (c.x  + c.z + up.y + dn.y - 4.f * c.y);
        o.z = c.z + f * (c.y  + c.w + up.z + dn.z - 4.f * c.z);
        o.w = c.w + f * (c.z  + right + up.w + dn.w - 4.f * c.w);
        o.x = fminf(fmaxf(o.x, 0.f), 1.f);
        o.y = fminf(fmaxf(o.y, 0.f), 1.f);
        o.z = fminf(fmaxf(o.z, 0.f), 1.f);
        o.w = fminf(fmaxf(o.w, 0.f), 1.f);
        *(float4*)(db + h * WW + w) = o;
    } else if (step == tb && (tb == 0 || (tb & 1))) {
        // ---- sample just finished; final data is not in `out` yet ----
        // t==0: data is x. t odd: last write was step t-1 (even) -> ws field.
        const float* cs = (tb == 0) ? x : fld;
        const float4* s4 = (const float4*)(cs + (size_t)b * HW);
        float4* d4 = (float4*)(out + (size_t)b * HW);
        const int flat4 = blockIdx.x * 256 + threadIdx.x;
        float4 v = s4[flat4];
        v.x = fminf(fmaxf(v.x, 0.f), 1.f);
        v.y = fminf(fmaxf(v.y, 0.f), 1.f);
        v.z = fminf(fmaxf(v.z, 0.f), 1.f);
        v.w = fminf(fmaxf(v.w, 0.f), 1.f);
        d4[flat4] = v;
    }
    // else: sample finished earlier; its data already sits in `out`. No-op.
}

extern "C" void kernel_launch(void* const* d_in, const int* in_sizes, int n_in,
                              void* d_out, int out_size, void* d_ws, size_t ws_size,
                              hipStream_t stream) {
    const float* x     = (const float*)d_in[0];
    const int*   t     = (const int*)d_in[1];
    const float* dcoef = (const float*)d_in[2];
    float* out = (float*)d_out;

    // ws layout (header 4 KiB, proven available in rounds 1-2):
    //   [fvec: 32 floats][partials: 32*16 floats] ... [field @ 4 KiB: 32 MiB]
    float* fvec     = (float*)d_ws;
    float* partials = fvec + BB;
    float* field    = (float*)((char*)d_ws + 4096);

    dim3 blk(256);
    reduce_x_kernel<<<dim3(RBLK, BB), blk, 0, stream>>>(x, t, partials);
    factor_kernel<<<dim3(BB), dim3(64), 0, stream>>>(partials, t, dcoef, fvec);

    for (int i = 0; i < T_STEPS; i++) {
        const float* src = (i == 0) ? x : ((i & 1) ? field : out);
        float* dst = (i & 1) ? out : field;
        step_kernel<<<dim3(256, BB), blk, 0, stream>>>(
            src, dst, x, field, out, t, fvec, i);
    }
}

// Round 5
// 117.253 us; speedup vs baseline: 6.3871x; 1.5590x over previous
//
#include <hip/hip_runtime.h>
#include <math.h>

// Problem constants (from reference)
#define BB 32
#define HH 512
#define WW 512
#define T_STEPS 16
#define DT_C 0.2f
#define HW (HH * WW)        // 262144 elements per sample (C=1)
#define RBLK 16             // reduce blocks per sample

// Temporal fusion parameters
#define NF 4                // Euler steps fused per dispatch
#define TS 64               // output tile (TS x TS)
#define IT (TS + 2 * NF)    // input tile with halo: 72
#define PAD 76              // LDS row stride in floats (72 + 4)

// ---------------------------------------------------------------------------
// Math fact (round 1): periodic Laplacian is mean-zero and f < 0.25 keeps
// y in [0,1] (clip never fires), so the per-sample mean is invariant and
// D = d_coef * sigmoid(mean(x)) is CONSTANT across steps.
// Round 2 lesson: no same-address atomics -> two-stage deterministic reduce.
// Round 3 lesson: fuse 4 steps/dispatch with LDS halo tiling.
// Round 4 lesson: at base=8 the finish-destination must be `field` (out is
// the stencil src there -> write hazard + copy912 stale-clobber). Explicit
// fdst parameter per dispatch; copy912 fixes t in [9,12] afterwards.
// ---------------------------------------------------------------------------

__device__ __forceinline__ float block_sum_256(float v) {
    __shared__ float lds[4];
#pragma unroll
    for (int off = 32; off > 0; off >>= 1)
        v += __shfl_down(v, off, 64);
    const int lane = threadIdx.x & 63;
    const int wid  = threadIdx.x >> 6;
    if (lane == 0) lds[wid] = v;
    __syncthreads();
    float s = 0.f;
    if (threadIdx.x == 0) s = lds[0] + lds[1] + lds[2] + lds[3];
    return s;
}

// Stage 1: per-block partial sums of x. grid: (RBLK, BB), block: 256.
__global__ __launch_bounds__(256) void reduce_x_kernel(
        const float* __restrict__ x, const int* __restrict__ t,
        float* __restrict__ partials) {
    const int b = blockIdx.y;
    if (t[b] <= 0) return;                 // D unused for t==0 samples
    const float4* xb = (const float4*)(x + (size_t)b * HW);
    float v = 0.f;
    const int base = blockIdx.x * (HW / 4 / RBLK);   // 4096 float4 per block
#pragma unroll
    for (int k = 0; k < 16; k++) {
        float4 c = xb[base + k * 256 + threadIdx.x];
        v += (c.x + c.y) + (c.z + c.w);
    }
    float s = block_sum_256(v);
    if (threadIdx.x == 0) partials[b * RBLK + blockIdx.x] = s;
}

// Stage 2: f[b] = d_coef * sigmoid(mean) * DT. grid: (BB), block: 64.
__global__ void factor_kernel(const float* __restrict__ partials,
                              const int* __restrict__ t,
                              const float* __restrict__ dcoef,
                              float* __restrict__ f) {
    const int b = blockIdx.x;
    float v = (threadIdx.x < RBLK && t[b] > 0)
                  ? partials[b * RBLK + threadIdx.x] : 0.f;
#pragma unroll
    for (int off = 8; off > 0; off >>= 1)
        v += __shfl_down(v, off, 64);
    if (threadIdx.x == 0) {
        const float mean = v * (1.0f / (float)HW);
        f[b] = dcoef[0] * (1.0f / (1.0f + expf(-mean))) * DT_C;
    }
}

// Fused kernel: up to NF Euler steps on a TSxTS tile, entirely in LDS.
// grid: (64, BB) -- 8x8 tiles of 64x64 per sample. block: 256.
// Garbage-shrink: input valid on [0,72)^2; computing the fixed interior
// [1,71)^2 each step shrinks validity one ring per step -> after k<=4 steps
// region [k,72-k)^2 is valid, containing the output region [4,68)^2.
__global__ __launch_bounds__(256) void fused_kernel(
        const float* __restrict__ src,   // stencil source buffer
        float* __restrict__ adst,        // destination: still-active samples
        float* __restrict__ fdst,        // destination: finishing samples
        const float* __restrict__ x,     // original input (t==0 copy, base==0)
        float* __restrict__ out,         // final output (t==0 copy dest)
        const int* __restrict__ t,
        const float* __restrict__ fvec,  // [BB] precomputed D*DT
        int base) {
    const int b = blockIdx.y;
    const int tb = t[b];
    const int tx = blockIdx.x & 7;
    const int ty = blockIdx.x >> 3;
    const int h0 = ty * TS;
    const int w0 = tx * TS;

    if (tb <= base) {
        if (base == 0 && tb == 0) {
            // copy x -> out (clip is a no-op on [0,1) input, applied anyway)
            const float4* s4 = (const float4*)(x + (size_t)b * HW);
            float4* d4 = (float4*)(out + (size_t)b * HW);
            for (int j = threadIdx.x; j < TS * (TS / 4); j += 256) {
                const int r = j >> 4, c4 = j & 15;
                const int idx = (h0 + r) * (WW / 4) + (w0 >> 2) + c4;
                float4 v = s4[idx];
                v.x = fminf(fmaxf(v.x, 0.f), 1.f);
                v.y = fminf(fmaxf(v.y, 0.f), 1.f);
                v.z = fminf(fmaxf(v.z, 0.f), 1.f);
                v.w = fminf(fmaxf(v.w, 0.f), 1.f);
                d4[idx] = v;
            }
        }
        return;   // sample finished earlier; data already in out
    }

    int nst = tb - base;
    if (nst > NF) nst = NF;
    const bool finishing = (tb <= base + NF);
    float* dstp = finishing ? fdst : adst;
    const float f = fvec[b];

    __shared__ __align__(16) float bufA[IT][PAD];
    __shared__ __align__(16) float bufB[IT][PAD];

    // ---- load 72 rows x 18 float4 (aligned; halo via periodic wrap) ----
    const float* sb = src + (size_t)b * HW;
    for (int j = threadIdx.x; j < IT * 18; j += 256) {
        const int r = j / 18;
        const int c = j - r * 18;
        const int gr  = (h0 - NF + r) & (HH - 1);
        const int gc4 = ((w0 >> 2) - 1 + c) & (WW / 4 - 1);
        const float4 v = *(const float4*)(sb + gr * WW + gc4 * 4);
        *(float4*)(&bufA[r][c * 4]) = v;
    }
    __syncthreads();

    // ---- nst in-LDS Euler steps on fixed interior [1,71)^2 ----
    float (*cur)[PAD] = bufA;
    float (*nxt)[PAD] = bufB;
    for (int s = 0; s < nst; s++) {
        for (int j = threadIdx.x; j < (IT - 2) * (IT - 2); j += 256) {
            const int r = j / (IT - 2) + 1;
            const int c = j % (IT - 2) + 1;
            const float ctr = cur[r][c];
            const float lap = cur[r - 1][c] + cur[r + 1][c]
                            + cur[r][c - 1] + cur[r][c + 1] - 4.f * ctr;
            const float v = fmaf(f, lap, ctr);
            nxt[r][c] = fminf(fmaxf(v, 0.f), 1.f);
        }
        float (*tmp)[PAD] = cur; cur = nxt; nxt = tmp;
        __syncthreads();
    }

    // ---- write 64x64 center to dst ----
    float* db = dstp + (size_t)b * HW;
    for (int j = threadIdx.x; j < TS * (TS / 4); j += 256) {
        const int r = j >> 4, c4 = j & 15;
        const float4 v = *(const float4*)(&cur[NF + r][NF + c4 * 4]);
        *(float4*)(db + (size_t)(h0 + r) * WW + w0 + c4 * 4) = v;
    }
}

// Fix-up: samples finishing at base=8 (t in [9,12]) have final data in
// `field`. grid: (256, BB).
__global__ __launch_bounds__(256) void copy912_kernel(
        const float* __restrict__ field, float* __restrict__ out,
        const int* __restrict__ t) {
    const int b = blockIdx.y;
    const int tb = t[b];
    if (tb < 9 || tb > 12) return;
    const float4* s4 = (const float4*)(field + (size_t)b * HW);
    float4* d4 = (float4*)(out + (size_t)b * HW);
    const int j = blockIdx.x * 256 + threadIdx.x;
    d4[j] = s4[j];
}

extern "C" void kernel_launch(void* const* d_in, const int* in_sizes, int n_in,
                              void* d_out, int out_size, void* d_ws, size_t ws_size,
                              hipStream_t stream) {
    const float* x     = (const float*)d_in[0];
    const int*   t     = (const int*)d_in[1];
    const float* dcoef = (const float*)d_in[2];
    float* out = (float*)d_out;

    // ws layout (header 4 KiB):
    //   [fvec: 32 floats][partials: 32*16 floats] ... [field @ 4 KiB: 32 MiB]
    float* fvec     = (float*)d_ws;
    float* partials = fvec + BB;
    float* field    = (float*)((char*)d_ws + 4096);

    reduce_x_kernel<<<dim3(RBLK, BB), dim3(256), 0, stream>>>(x, t, partials);
    factor_kernel<<<dim3(BB), dim3(64), 0, stream>>>(partials, t, dcoef, fvec);

    // 4 fused dispatches: src chain x -> field -> out -> field -> out.
    // fdst = out except base=8 (src==out there -> finishing goes to field).
    fused_kernel<<<dim3(64, BB), dim3(256), 0, stream>>>(x,     field, out,   x, out, t, fvec, 0);
    fused_kernel<<<dim3(64, BB), dim3(256), 0, stream>>>(field, out,   out,   x, out, t, fvec, 4);
    fused_kernel<<<dim3(64, BB), dim3(256), 0, stream>>>(out,   field, field, x, out, t, fvec, 8);
    fused_kernel<<<dim3(64, BB), dim3(256), 0, stream>>>(field, out,   out,   x, out, t, fvec, 12);

    copy912_kernel<<<dim3(HW / 4 / 256, BB), dim3(256), 0, stream>>>(field, out, t);
}

// Round 6
// 90.771 us; speedup vs baseline: 8.2505x; 1.2917x over previous
//
#include <hip/hip_runtime.h>
#include <math.h>

// Problem constants (from reference)
#define BB 32
#define HH 512
#define WW 512
#define T_STEPS 16
#define DT_C 0.2f
#define HW (HH * WW)        // 262144 elements per sample (C=1)
#define RBLK 16             // reduce blocks per sample

// Temporal fusion parameters (NF=4 steps per dispatch)
#define NF 4
#define TS 64               // output tile (TS x TS)
#define ITR 74              // input tile rows  (halo 5 top/bottom)
#define ITC 80              // input tile cols  (halo 8 left, 8 right)
#define PADC 84             // LDS row stride (84 % 32 = 20: staggers strip banks)

// ---------------------------------------------------------------------------
// Math fact (round 1): periodic Laplacian is mean-zero and f < 0.25 keeps
// y in [0,1] (clip never fires), so the per-sample mean is invariant and
// D = d_coef * sigmoid(mean(x)) is CONSTANT across steps.
// Round 2: no same-address atomics -> two-stage deterministic reduce.
// Round 3: fuse 4 steps/dispatch with LDS halo tiling.
// Round 4: finish-destination must never alias the stencil src.
// Round 5: scalar in-LDS stencil was LDS-instruction-bound (~0.54 cyc/cell).
//   -> 6-row x float4 strips: 8 ds_read_b128 + 12 b32 + 6 ds_write_b128 per
//      24 cells (~0.16 cyc/cell), vertical neighbors reused in registers.
//   -> two ws fields (x->f1->f2->f1->out): fdst is ALWAYS out, no fix-up pass.
// Geometry: input rows [h0-5,h0+69) -> local r; cols [w0-8,w0+72) -> local c.
//   Compute rows [1,73) (12 strips x 6), cols [4,76) (18 float4 groups).
//   Validity after k steps: rows [k, 74-k-... ] -- concretely after 4 steps
//   rows [4,70) >= output [5,69), cols [7,73) >= output [8,72). Margins +1.
// ---------------------------------------------------------------------------

__device__ __forceinline__ float block_sum_256(float v) {
    __shared__ float lds[4];
#pragma unroll
    for (int off = 32; off > 0; off >>= 1)
        v += __shfl_down(v, off, 64);
    const int lane = threadIdx.x & 63;
    const int wid  = threadIdx.x >> 6;
    if (lane == 0) lds[wid] = v;
    __syncthreads();
    float s = 0.f;
    if (threadIdx.x == 0) s = lds[0] + lds[1] + lds[2] + lds[3];
    return s;
}

// Stage 1: per-block partial sums of x. grid: (RBLK, BB), block: 256.
__global__ __launch_bounds__(256) void reduce_x_kernel(
        const float* __restrict__ x, const int* __restrict__ t,
        float* __restrict__ partials) {
    const int b = blockIdx.y;
    if (t[b] <= 0) return;                 // D unused for t==0 samples
    const float4* xb = (const float4*)(x + (size_t)b * HW);
    float v = 0.f;
    const int base = blockIdx.x * (HW / 4 / RBLK);   // 4096 float4 per block
#pragma unroll
    for (int k = 0; k < 16; k++) {
        float4 c = xb[base + k * 256 + threadIdx.x];
        v += (c.x + c.y) + (c.z + c.w);
    }
    float s = block_sum_256(v);
    if (threadIdx.x == 0) partials[b * RBLK + blockIdx.x] = s;
}

// Stage 2: f[b] = d_coef * sigmoid(mean) * DT. grid: (BB), block: 64.
__global__ void factor_kernel(const float* __restrict__ partials,
                              const int* __restrict__ t,
                              const float* __restrict__ dcoef,
                              float* __restrict__ f) {
    const int b = blockIdx.x;
    float v = (threadIdx.x < RBLK && t[b] > 0)
                  ? partials[b * RBLK + threadIdx.x] : 0.f;
#pragma unroll
    for (int off = 8; off > 0; off >>= 1)
        v += __shfl_down(v, off, 64);
    if (threadIdx.x == 0) {
        const float mean = v * (1.0f / (float)HW);
        f[b] = dcoef[0] * (1.0f / (1.0f + expf(-mean))) * DT_C;
    }
}

// Fused kernel: up to NF Euler steps on a TSxTS tile, entirely in LDS.
// grid: (64, BB) -- 8x8 tiles of 64x64 per sample. block: 256.
__global__ __launch_bounds__(256) void fused_kernel(
        const float* __restrict__ src,   // stencil source buffer
        float* __restrict__ adst,        // destination: still-active samples
        float* __restrict__ fdst,        // destination: finishing samples (== out)
        const float* __restrict__ x,     // original input (t==0 copy, base==0)
        float* __restrict__ out,         // final output (t==0 copy dest)
        const int* __restrict__ t,
        const float* __restrict__ fvec,  // [BB] precomputed D*DT
        int base) {
    const int b = blockIdx.y;
    const int tb = t[b];
    const int tx = blockIdx.x & 7;
    const int ty = blockIdx.x >> 3;
    const int h0 = ty * TS;
    const int w0 = tx * TS;

    if (tb <= base) {
        if (base == 0 && tb == 0) {
            // copy x -> out (clip is a near-no-op on [0,1) input)
            const float4* s4 = (const float4*)(x + (size_t)b * HW);
            float4* d4 = (float4*)(out + (size_t)b * HW);
            for (int j = threadIdx.x; j < TS * (TS / 4); j += 256) {
                const int r = j >> 4, c4 = j & 15;
                const int idx = (h0 + r) * (WW / 4) + (w0 >> 2) + c4;
                float4 v = s4[idx];
                v.x = fminf(fmaxf(v.x, 0.f), 1.f);
                v.y = fminf(fmaxf(v.y, 0.f), 1.f);
                v.z = fminf(fmaxf(v.z, 0.f), 1.f);
                v.w = fminf(fmaxf(v.w, 0.f), 1.f);
                d4[idx] = v;
            }
        }
        return;   // sample finished earlier; data already in out
    }

    int nst = tb - base;
    if (nst > NF) nst = NF;
    float* dstp = (tb <= base + NF) ? fdst : adst;
    const float f = fvec[b];

    __shared__ __align__(16) float bufA[ITR][PADC];
    __shared__ __align__(16) float bufB[ITR][PADC];

    // ---- load 74 rows x 20 float4 (aligned; halo via periodic wrap) ----
    const float* sb = src + (size_t)b * HW;
    for (int j = threadIdx.x; j < ITR * (ITC / 4); j += 256) {
        const int r  = j / (ITC / 4);
        const int cg = j - r * (ITC / 4);
        const int gr  = (h0 - 5 + r) & (HH - 1);
        const int gc4 = ((w0 >> 2) - 2 + cg) & (WW / 4 - 1);
        *(float4*)(&bufA[r][cg * 4]) = *(const float4*)(sb + gr * WW + gc4 * 4);
    }
    __syncthreads();

    // ---- nst in-LDS Euler steps: 12 six-row strips x 18 float4 groups ----
    const int st = threadIdx.x / 18;           // strip index (valid if tid<216)
    const int g  = threadIdx.x - st * 18;      // float4 column group
    const int r0 = 6 * st;                     // topmost read row
    const int cb = 4 + 4 * g;                  // center column base

    float (*cur)[PADC] = bufA;
    float (*nxt)[PADC] = bufB;
    for (int s = 0; s < nst; s++) {
        if (threadIdx.x < 216) {
            float4 row[8];
#pragma unroll
            for (int k = 0; k < 8; k++)
                row[k] = *(const float4*)(&cur[r0 + k][cb]);
#pragma unroll
            for (int k = 0; k < 6; k++) {
                const float L = cur[r0 + 1 + k][cb - 1];
                const float R = cur[r0 + 1 + k][cb + 4];
                const float4 c = row[k + 1];
                const float4 u = row[k];
                const float4 d = row[k + 2];
                float4 o;
                o.x = fmaf(f, L   + c.y + u.x + d.x - 4.f * c.x, c.x);
                o.y = fmaf(f, c.x + c.z + u.y + d.y - 4.f * c.y, c.y);
                o.z = fmaf(f, c.y + c.w + u.z + d.z - 4.f * c.z, c.z);
                o.w = fmaf(f, c.z + R   + u.w + d.w - 4.f * c.w, c.w);
                o.x = fminf(fmaxf(o.x, 0.f), 1.f);
                o.y = fminf(fmaxf(o.y, 0.f), 1.f);
                o.z = fminf(fmaxf(o.z, 0.f), 1.f);
                o.w = fminf(fmaxf(o.w, 0.f), 1.f);
                *(float4*)(&nxt[r0 + 1 + k][cb]) = o;
            }
        }
        __syncthreads();
        float (*tmp)[PADC] = cur; cur = nxt; nxt = tmp;
    }

    // ---- write 64x64 center (local rows [5,69), cols [8,72)) ----
    float* db = dstp + (size_t)b * HW;
    for (int j = threadIdx.x; j < TS * (TS / 4); j += 256) {
        const int r = j >> 4, c4 = j & 15;
        const float4 v = *(const float4*)(&cur[5 + r][8 + c4 * 4]);
        *(float4*)(db + (size_t)(h0 + r) * WW + w0 + c4 * 4) = v;
    }
}

extern "C" void kernel_launch(void* const* d_in, const int* in_sizes, int n_in,
                              void* d_out, int out_size, void* d_ws, size_t ws_size,
                              hipStream_t stream) {
    const float* x     = (const float*)d_in[0];
    const int*   t     = (const int*)d_in[1];
    const float* dcoef = (const float*)d_in[2];
    float* out = (float*)d_out;

    // ws layout (header 4 KiB):
    //   [fvec: 32 floats][partials: 32*16 floats]
    //   [f1 @ 4 KiB: 32 MiB][f2 @ 4 KiB + 32 MiB: 32 MiB]
    float* fvec     = (float*)d_ws;
    float* partials = fvec + BB;
    float* f1       = (float*)((char*)d_ws + 4096);
    float* f2       = f1 + (size_t)BB * HW;

    reduce_x_kernel<<<dim3(RBLK, BB), dim3(256), 0, stream>>>(x, t, partials);
    factor_kernel<<<dim3(BB), dim3(64), 0, stream>>>(partials, t, dcoef, fvec);

    // Chain x -> f1 -> f2 -> f1 -> out; finishing samples always write out
    // (src never aliases out -> no hazard, no fix-up pass).
    fused_kernel<<<dim3(64, BB), dim3(256), 0, stream>>>(x,  f1,  out, x, out, t, fvec, 0);
    fused_kernel<<<dim3(64, BB), dim3(256), 0, stream>>>(f1, f2,  out, x, out, t, fvec, 4);
    fused_kernel<<<dim3(64, BB), dim3(256), 0, stream>>>(f2, f1,  out, x, out, t, fvec, 8);
    fused_kernel<<<dim3(64, BB), dim3(256), 0, stream>>>(f1, out, out, x, out, t, fvec, 12);
}

// Round 7
// 74.223 us; speedup vs baseline: 10.0899x; 1.2229x over previous
//
#include <hip/hip_runtime.h>
#include <math.h>

// Problem constants (from reference)
#define BB 32
#define HH 512
#define WW 512
#define T_STEPS 16
#define DT_C 0.2f
#define HW (HH * WW)        // 262144 elements per sample (C=1)
#define RBLK 16             // reduce blocks per sample

// Temporal fusion parameters (NF=4 steps per dispatch)
#define NF 4
#define TS 64               // output tile (TS x TS)
#define ITR 74              // input tile rows  (halo 5 top/bottom)
#define ITC 80              // input tile cols  (halo 8 left, 8 right)
#define PADC 84             // LDS row stride

// ---------------------------------------------------------------------------
// Round 1: periodic Laplacian is mean-zero and f<0.25 keeps y in [0,1]
//   (clip never fires) -> D = d_coef*sigmoid(mean(x)) is CONSTANT.
// Round 2: no same-address atomics -> two-stage deterministic reduce.
// Round 3: fuse 4 steps/dispatch with LDS halo tiling.
// Round 4: finish-destination must never alias the stencil src.
// Round 5: vectorize the in-LDS stencil (6-row float4 strips).
// Round 6: still LDS-instruction-bound (~238 LDS cyc/wave-step). -> keep the
//   strip REGISTER-RESIDENT across steps; LDS only exchanges halo rows
//   (2 wr + 2 rd b128) and __shfl provides horizontal neighbors (12 bperm).
//   Lane map: 3 strips x 20 col-groups per wave (lanes 60-63 idle) so all
//   cross-strip shfl garbage lands in garbage-shrink cols 0/79.
//   Validity after 4 steps: rows [4,70) >= out rows [5,69); cols [4,76) >=
//   out cols [8,72). Also fold factor_kernel into fused (uniform scalar sum).
// ---------------------------------------------------------------------------

__device__ __forceinline__ float block_sum_256(float v) {
    __shared__ float lds[4];
#pragma unroll
    for (int off = 32; off > 0; off >>= 1)
        v += __shfl_down(v, off, 64);
    const int lane = threadIdx.x & 63;
    const int wid  = threadIdx.x >> 6;
    if (lane == 0) lds[wid] = v;
    __syncthreads();
    float s = 0.f;
    if (threadIdx.x == 0) s = lds[0] + lds[1] + lds[2] + lds[3];
    return s;
}

// Stage 1: per-block partial sums of x. grid: (RBLK, BB), block: 256.
__global__ __launch_bounds__(256) void reduce_x_kernel(
        const float* __restrict__ x, const int* __restrict__ t,
        float* __restrict__ partials) {
    const int b = blockIdx.y;
    if (t[b] <= 0) return;                 // D unused for t==0 samples
    const float4* xb = (const float4*)(x + (size_t)b * HW);
    float v = 0.f;
    const int base = blockIdx.x * (HW / 4 / RBLK);   // 4096 float4 per block
#pragma unroll
    for (int k = 0; k < 16; k++) {
        float4 c = xb[base + k * 256 + threadIdx.x];
        v += (c.x + c.y) + (c.z + c.w);
    }
    float s = block_sum_256(v);
    if (threadIdx.x == 0) partials[b * RBLK + blockIdx.x] = s;
}

// Fused kernel: up to NF Euler steps, field register-resident.
// grid: (64, BB) -- 8x8 tiles of 64x64 per sample. block: 256.
__global__ __launch_bounds__(256) void fused_kernel(
        const float* __restrict__ src,   // stencil source buffer
        float* __restrict__ adst,        // destination: still-active samples
        float* __restrict__ fdst,        // destination: finishing samples (== out)
        const float* __restrict__ x,     // original input (t==0 copy, base==0)
        float* __restrict__ out,         // final output (t==0 copy dest)
        const int* __restrict__ t,
        const float* __restrict__ partials,
        const float* __restrict__ dcoef,
        int base) {
    const int b = blockIdx.y;
    const int tb = t[b];
    const int tx = blockIdx.x & 7;
    const int ty = blockIdx.x >> 3;
    const int h0 = ty * TS;
    const int w0 = tx * TS;

    if (tb <= base) {
        if (base == 0 && tb == 0) {
            // copy x -> out (clip applied; near-no-op on [0,1) input)
            const float4* s4 = (const float4*)(x + (size_t)b * HW);
            float4* d4 = (float4*)(out + (size_t)b * HW);
            for (int j = threadIdx.x; j < TS * (TS / 4); j += 256) {
                const int r = j >> 4, c4 = j & 15;
                const int idx = (h0 + r) * (WW / 4) + (w0 >> 2) + c4;
                float4 v = s4[idx];
                v.x = fminf(fmaxf(v.x, 0.f), 1.f);
                v.y = fminf(fmaxf(v.y, 0.f), 1.f);
                v.z = fminf(fmaxf(v.z, 0.f), 1.f);
                v.w = fminf(fmaxf(v.w, 0.f), 1.f);
                d4[idx] = v;
            }
        }
        return;   // sample finished earlier; data already in out
    }

    int nst = tb - base;
    if (nst > NF) nst = NF;
    float* dstp = (tb <= base + NF) ? fdst : adst;

    // f computed inline (block-uniform, deterministic sequential sum)
    float psum = 0.f;
#pragma unroll
    for (int k = 0; k < RBLK; k++) psum += partials[b * RBLK + k];
    const float f = dcoef[0] * (1.0f / (1.0f + expf(-psum * (1.0f / (float)HW)))) * DT_C;

    __shared__ __align__(16) float buf[ITR][PADC];

    // ---- stage 74 rows x 20 float4 (aligned; halo via periodic wrap) ----
    const float* sb = src + (size_t)b * HW;
    for (int j = threadIdx.x; j < ITR * (ITC / 4); j += 256) {
        const int r  = j / (ITC / 4);
        const int cg = j - r * (ITC / 4);
        const int gr  = (h0 - 5 + r) & (HH - 1);
        const int gc4 = ((w0 >> 2) - 2 + cg) & (WW / 4 - 1);
        *(float4*)(&buf[r][cg * 4]) = *(const float4*)(sb + gr * WW + gc4 * 4);
    }
    __syncthreads();

    // ---- lane mapping: 3 strips x 20 col-groups per wave ----
    const int ln  = threadIdx.x & 63;
    const int siw = ln / 20;                    // 0..2 active, 3 = idle
    const int g   = ln - siw * 20;              // column group 0..19
    const int s   = (threadIdx.x >> 6) * 3 + siw;   // strip 0..11
    const bool act = (siw < 3);
    const int r1 = 1 + 6 * s;                   // first owned row
    const int cb = 4 * g;                       // column base in tile

    float4 cur[6];
    if (act) {
#pragma unroll
        for (int j = 0; j < 6; j++)
            cur[j] = *(const float4*)(&buf[r1 + j][cb]);
    }

    // ---- nst register-resident Euler steps ----
    for (int it = 0; it < nst; it++) {
        if (act) {
            const float4 h0v = *(const float4*)(&buf[r1 - 1][cb]);
            const float4 h7v = *(const float4*)(&buf[r1 + 6][cb]);
            float4 n[6];
#pragma unroll
            for (int j = 0; j < 6; j++) {
                const float4 c = cur[j];
                const float4 u = (j == 0) ? h0v : cur[j - 1];
                const float4 d = (j == 5) ? h7v : cur[j + 1];
                const float L = __shfl_up(c.w, 1, 64);    // lane-1's col cb-1
                const float R = __shfl_down(c.x, 1, 64);  // lane+1's col cb+4
                float4 o;
                o.x = fmaf(f, L   + c.y + u.x + d.x - 4.f * c.x, c.x);
                o.y = fmaf(f, c.x + c.z + u.y + d.y - 4.f * c.y, c.y);
                o.z = fmaf(f, c.y + c.w + u.z + d.z - 4.f * c.z, c.z);
                o.w = fmaf(f, c.z + R   + u.w + d.w - 4.f * c.w, c.w);
                o.x = fminf(fmaxf(o.x, 0.f), 1.f);
                o.y = fminf(fmaxf(o.y, 0.f), 1.f);
                o.z = fminf(fmaxf(o.z, 0.f), 1.f);
                o.w = fminf(fmaxf(o.w, 0.f), 1.f);
                n[j] = o;
            }
#pragma unroll
            for (int j = 0; j < 6; j++) cur[j] = n[j];
        }
        __syncthreads();    // halo reads of this step complete
        if (act) {
            *(float4*)(&buf[r1][cb])     = cur[0];   // top row -> strip s-1's halo
            *(float4*)(&buf[r1 + 5][cb]) = cur[5];   // bottom row -> strip s+1's halo
        }
        __syncthreads();    // halo writes visible for next step
    }

    // ---- write 64x64 center from registers (rows [5,69), cols [8,72)) ----
    if (act && g >= 2 && g < 18) {
        float* db = dstp + (size_t)b * HW;
        const int gcol = w0 - 8 + cb;
#pragma unroll
        for (int j = 0; j < 6; j++) {
            const int lr = r1 + j;
            if (lr >= 5 && lr < 69)
                *(float4*)(db + (size_t)(h0 + lr - 5) * WW + gcol) = cur[j];
        }
    }
}

extern "C" void kernel_launch(void* const* d_in, const int* in_sizes, int n_in,
                              void* d_out, int out_size, void* d_ws, size_t ws_size,
                              hipStream_t stream) {
    const float* x     = (const float*)d_in[0];
    const int*   t     = (const int*)d_in[1];
    const float* dcoef = (const float*)d_in[2];
    float* out = (float*)d_out;

    // ws layout (header 4 KiB):
    //   [partials: 32*16 floats]
    //   [f1 @ 4 KiB: 32 MiB][f2 @ 4 KiB + 32 MiB: 32 MiB]
    float* partials = (float*)d_ws;
    float* f1       = (float*)((char*)d_ws + 4096);
    float* f2       = f1 + (size_t)BB * HW;

    reduce_x_kernel<<<dim3(RBLK, BB), dim3(256), 0, stream>>>(x, t, partials);

    // Chain x -> f1 -> f2 -> f1 -> out; finishing samples always write out
    // (src never aliases out -> no hazard, no fix-up pass).
    fused_kernel<<<dim3(64, BB), dim3(256), 0, stream>>>(x,  f1,  out, x, out, t, partials, dcoef, 0);
    fused_kernel<<<dim3(64, BB), dim3(256), 0, stream>>>(f1, f2,  out, x, out, t, partials, dcoef, 4);
    fused_kernel<<<dim3(64, BB), dim3(256), 0, stream>>>(f2, f1,  out, x, out, t, partials, dcoef, 8);
    fused_kernel<<<dim3(64, BB), dim3(256), 0, stream>>>(f1, out, out, x, out, t, partials, dcoef, 12);
}

// Round 8
// 56.336 us; speedup vs baseline: 13.2936x; 1.3175x over previous
//
#include <hip/hip_runtime.h>
#include <math.h>

// Problem constants (from reference)
#define BB 32
#define HH 512
#define WW 512
#define T_STEPS 16
#define DT_C 0.2f
#define HW (HH * WW)        // 262144 elements per sample (C=1)
#define RBLK 16             // reduce blocks per sample

// Temporal fusion parameters (NF=8 steps per dispatch, 2 dispatches)
#define NF 8
#define TS 64               // output tile (TS x TS)
#define ITR 86              // input tile rows: 12 strips x 7 + 2 halo rows
#define ITC 80              // input tile cols (halo 8 left, 8 right)
#define PADC 84             // LDS row stride (84 % 32 = 20 staggers banks)

// ---------------------------------------------------------------------------
// Round 1: periodic Laplacian is mean-zero and f<0.25 keeps y in [0,1]
//   (clip never fires) -> D = d_coef*sigmoid(mean(x)) is CONSTANT.
// Round 2: no same-address atomics -> two-stage deterministic reduce.
// Round 3: fuse steps/dispatch with LDS halo tiling.
// Round 4: finish-destination must never alias the stencil src.
// Round 5: vectorize the in-LDS stencil (float4 strips).
// Round 6: register-resident strips; LDS only for halo rows; shfl for L/R.
// Round 7: per-dispatch staging (36 MiB rd + 32 MiB wr through L2/L3) is the
//   remaining fixed cost -> NF=8, 2 dispatches (x -> f1 -> out), strips of
//   7 rows (12 strips x 7 = 84 computed rows, tile 86 rows).
//   Validity after k<=8 steps: rows [k,86-k) -> [8,78) >= out rows [11,75);
//   cols [k,80-k) -> [8,72) == out cols exactly.
// ---------------------------------------------------------------------------

__device__ __forceinline__ float block_sum_256(float v) {
    __shared__ float lds[4];
#pragma unroll
    for (int off = 32; off > 0; off >>= 1)
        v += __shfl_down(v, off, 64);
    const int lane = threadIdx.x & 63;
    const int wid  = threadIdx.x >> 6;
    if (lane == 0) lds[wid] = v;
    __syncthreads();
    float s = 0.f;
    if (threadIdx.x == 0) s = lds[0] + lds[1] + lds[2] + lds[3];
    return s;
}

// Stage 1: per-block partial sums of x. grid: (RBLK, BB), block: 256.
__global__ __launch_bounds__(256) void reduce_x_kernel(
        const float* __restrict__ x, const int* __restrict__ t,
        float* __restrict__ partials) {
    const int b = blockIdx.y;
    if (t[b] <= 0) return;                 // D unused for t==0 samples
    const float4* xb = (const float4*)(x + (size_t)b * HW);
    float v = 0.f;
    const int base = blockIdx.x * (HW / 4 / RBLK);   // 4096 float4 per block
#pragma unroll
    for (int k = 0; k < 16; k++) {
        float4 c = xb[base + k * 256 + threadIdx.x];
        v += (c.x + c.y) + (c.z + c.w);
    }
    float s = block_sum_256(v);
    if (threadIdx.x == 0) partials[b * RBLK + blockIdx.x] = s;
}

// Fused kernel: up to NF Euler steps, field register-resident (7-row strips).
// grid: (64, BB) -- 8x8 tiles of 64x64 per sample. block: 256.
__global__ __launch_bounds__(256) void fused_kernel(
        const float* __restrict__ src,   // stencil source buffer
        float* __restrict__ adst,        // destination: still-active samples
        float* __restrict__ fdst,        // destination: finishing samples (== out)
        const float* __restrict__ x,     // original input (t==0 copy, base==0)
        float* __restrict__ out,         // final output (t==0 copy dest)
        const int* __restrict__ t,
        const float* __restrict__ partials,
        const float* __restrict__ dcoef,
        int base) {
    const int b = blockIdx.y;
    const int tb = t[b];
    const int tx = blockIdx.x & 7;
    const int ty = blockIdx.x >> 3;
    const int h0 = ty * TS;
    const int w0 = tx * TS;

    if (tb <= base) {
        if (base == 0 && tb == 0) {
            // copy x -> out (clip applied; near-no-op on [0,1) input)
            const float4* s4 = (const float4*)(x + (size_t)b * HW);
            float4* d4 = (float4*)(out + (size_t)b * HW);
            for (int j = threadIdx.x; j < TS * (TS / 4); j += 256) {
                const int r = j >> 4, c4 = j & 15;
                const int idx = (h0 + r) * (WW / 4) + (w0 >> 2) + c4;
                float4 v = s4[idx];
                v.x = fminf(fmaxf(v.x, 0.f), 1.f);
                v.y = fminf(fmaxf(v.y, 0.f), 1.f);
                v.z = fminf(fmaxf(v.z, 0.f), 1.f);
                v.w = fminf(fmaxf(v.w, 0.f), 1.f);
                d4[idx] = v;
            }
        }
        return;   // sample finished earlier; data already in out
    }

    int nst = tb - base;
    if (nst > NF) nst = NF;
    float* dstp = (tb <= base + NF) ? fdst : adst;

    // f computed inline (block-uniform, deterministic sequential sum)
    float psum = 0.f;
#pragma unroll
    for (int k = 0; k < RBLK; k++) psum += partials[b * RBLK + k];
    const float f = dcoef[0] * (1.0f / (1.0f + expf(-psum * (1.0f / (float)HW)))) * DT_C;

    __shared__ __align__(16) float buf[ITR][PADC];

    // ---- stage 86 rows x 20 float4 (aligned; halo via periodic wrap) ----
    // local row r <-> global row h0 - 11 + r; local col c <-> w0 - 8 + c
    const float* sb = src + (size_t)b * HW;
    for (int j = threadIdx.x; j < ITR * (ITC / 4); j += 256) {
        const int r  = j / (ITC / 4);
        const int cg = j - r * (ITC / 4);
        const int gr  = (h0 - 11 + r) & (HH - 1);
        const int gc4 = ((w0 >> 2) - 2 + cg) & (WW / 4 - 1);
        *(float4*)(&buf[r][cg * 4]) = *(const float4*)(sb + gr * WW + gc4 * 4);
    }
    __syncthreads();

    // ---- lane mapping: 3 strips x 20 col-groups per wave ----
    const int ln  = threadIdx.x & 63;
    const int siw = ln / 20;                    // 0..2 active, 3 = idle
    const int g   = ln - siw * 20;              // column group 0..19
    const int s   = (threadIdx.x >> 6) * 3 + siw;   // strip 0..11
    const bool act = (siw < 3);
    const int r1 = 1 + 7 * s;                   // first owned row (1..78)
    const int cb = 4 * g;                       // column base in tile

    float4 cur[7];
    if (act) {
#pragma unroll
        for (int j = 0; j < 7; j++)
            cur[j] = *(const float4*)(&buf[r1 + j][cb]);
    }

    // ---- nst register-resident Euler steps (up-carry, in-place) ----
    for (int it = 0; it < nst; it++) {
        if (act) {
            float4 up = *(const float4*)(&buf[r1 - 1][cb]);
            const float4 h8v = *(const float4*)(&buf[r1 + 7][cb]);
#pragma unroll
            for (int j = 0; j < 7; j++) {
                const float4 c = cur[j];
                const float4 d = (j == 6) ? h8v : cur[j + 1];
                const float L = __shfl_up(c.w, 1, 64);    // lane-1's col cb-1
                const float R = __shfl_down(c.x, 1, 64);  // lane+1's col cb+4
                float4 o;
                o.x = fmaf(f, L   + c.y + up.x + d.x - 4.f * c.x, c.x);
                o.y = fmaf(f, c.x + c.z + up.y + d.y - 4.f * c.y, c.y);
                o.z = fmaf(f, c.y + c.w + up.z + d.z - 4.f * c.z, c.z);
                o.w = fmaf(f, c.z + R   + up.w + d.w - 4.f * c.w, c.w);
                o.x = fminf(fmaxf(o.x, 0.f), 1.f);
                o.y = fminf(fmaxf(o.y, 0.f), 1.f);
                o.z = fminf(fmaxf(o.z, 0.f), 1.f);
                o.w = fminf(fmaxf(o.w, 0.f), 1.f);
                cur[j] = o;
                up = c;
            }
        }
        __syncthreads();    // halo reads of this step complete
        if (act) {
            *(float4*)(&buf[r1][cb])     = cur[0];   // top row -> strip s-1's halo
            *(float4*)(&buf[r1 + 6][cb]) = cur[6];   // bottom row -> strip s+1's halo
        }
        __syncthreads();    // halo writes visible for next step
    }

    // ---- write 64x64 center from registers (rows [11,75), cols [8,72)) ----
    if (act && g >= 2 && g < 18) {
        float* db = dstp + (size_t)b * HW;
        const int gcol = w0 - 8 + cb;
#pragma unroll
        for (int j = 0; j < 7; j++) {
            const int lr = r1 + j;
            if (lr >= 11 && lr < 75)
                *(float4*)(db + (size_t)(h0 + lr - 11) * WW + gcol) = cur[j];
        }
    }
}

extern "C" void kernel_launch(void* const* d_in, const int* in_sizes, int n_in,
                              void* d_out, int out_size, void* d_ws, size_t ws_size,
                              hipStream_t stream) {
    const float* x     = (const float*)d_in[0];
    const int*   t     = (const int*)d_in[1];
    const float* dcoef = (const float*)d_in[2];
    float* out = (float*)d_out;

    // ws layout (header 4 KiB): [partials: 32*16 floats][f1 @ 4 KiB: 32 MiB]
    float* partials = (float*)d_ws;
    float* f1       = (float*)((char*)d_ws + 4096);

    reduce_x_kernel<<<dim3(RBLK, BB), dim3(256), 0, stream>>>(x, t, partials);

    // Chain x -> f1 -> out; finishing samples always write out
    // (src never aliases out -> no hazard, no fix-up pass).
    fused_kernel<<<dim3(64, BB), dim3(256), 0, stream>>>(x,  f1, out, x, out, t, partials, dcoef, 0);
    fused_kernel<<<dim3(64, BB), dim3(256), 0, stream>>>(f1, f1, out, x, out, t, partials, dcoef, 8);
}

// Round 9
// 52.833 us; speedup vs baseline: 14.1749x; 1.0663x over previous
//
#include <hip/hip_runtime.h>
#include <math.h>

// Problem constants (from reference)
#define BB 32
#define HH 512
#define WW 512
#define T_STEPS 16
#define DT_C 0.2f
#define HW (HH * WW)        // 262144 elements per sample (C=1)
#define RBLK 16             // reduce blocks per sample

// Temporal fusion parameters (NF=8 steps per dispatch, 2 dispatches)
#define NF 8
#define TSC 64              // output tile cols
#define TSR 128             // output tile rows
#define ITR 146             // input rows: 24 strips x 6 + 2 static halo rows
#define ITC 80              // input cols (halo 8 left, 8 right)
#define NSLOT 50            // LDS publish rows: static0 + 24x{top,bot} + static145
#define SLOTW 84            // LDS slot stride in floats

// ---------------------------------------------------------------------------
// Round 1: periodic Laplacian is mean-zero and f<0.25 keeps y in [0,1]
//   (clip never fires) -> D = d_coef*sigmoid(mean(x)) is CONSTANT.
// Round 2: no same-address atomics -> two-stage deterministic reduce.
// Round 3: fuse steps/dispatch with LDS halo tiling.
// Round 4: finish-destination must never alias the stencil src.
// Round 5/6/7: vectorize; register-resident strips; NF=8 x 2 dispatches.
// Round 8: LDS pipe is the long pole (4.6 cyc/cell: 14 bperm + 4 ds/step).
//   -> 8-col-wide threads (2 shfl per 8 cols), 64x128 tiles (redundancy
//      1.68->1.43), strips load global->registers directly; LDS is only a
//      50-row publish buffer (strip top/bottom + 2 static halo rows).
//   Slot map: strip s: top->2s+1, bottom->2s+2; reads up from 2s (bottom of
//   s-1; slot 0 = static row 0), down from 2s+3 (top of s+1; slot 49 =
//   static row 145).
//   Validity after k<=8 steps: rows [k,146-k) -> [8,138) >= out [9,137);
//   cols [k,80-k) -> [8,72) == out cols exactly (creep from shfl-edge
//   garbage at cols 0/79, incl. cross-strip shfl at group boundaries).
// ---------------------------------------------------------------------------

__device__ __forceinline__ float block_sum_256(float v) {
    __shared__ float lds[4];
#pragma unroll
    for (int off = 32; off > 0; off >>= 1)
        v += __shfl_down(v, off, 64);
    const int lane = threadIdx.x & 63;
    const int wid  = threadIdx.x >> 6;
    if (lane == 0) lds[wid] = v;
    __syncthreads();
    float s = 0.f;
    if (threadIdx.x == 0) s = lds[0] + lds[1] + lds[2] + lds[3];
    return s;
}

// Stage 1: per-block partial sums of x. grid: (RBLK, BB), block: 256.
__global__ __launch_bounds__(256) void reduce_x_kernel(
        const float* __restrict__ x, const int* __restrict__ t,
        float* __restrict__ partials) {
    const int b = blockIdx.y;
    if (t[b] <= 0) return;                 // D unused for t==0 samples
    const float4* xb = (const float4*)(x + (size_t)b * HW);
    float v = 0.f;
    const int base = blockIdx.x * (HW / 4 / RBLK);   // 4096 float4 per block
#pragma unroll
    for (int k = 0; k < 16; k++) {
        float4 c = xb[base + k * 256 + threadIdx.x];
        v += (c.x + c.y) + (c.z + c.w);
    }
    float s = block_sum_256(v);
    if (threadIdx.x == 0) partials[b * RBLK + blockIdx.x] = s;
}

__device__ __forceinline__ float4 clamp4(float4 v) {
    v.x = fminf(fmaxf(v.x, 0.f), 1.f);
    v.y = fminf(fmaxf(v.y, 0.f), 1.f);
    v.z = fminf(fmaxf(v.z, 0.f), 1.f);
    v.w = fminf(fmaxf(v.w, 0.f), 1.f);
    return v;
}

// Fused kernel: up to NF Euler steps, field register-resident (6-row x 8-col
// per thread). grid: (32, BB) -- 8 col-tiles x 4 row-tiles. block: 256.
__global__ __launch_bounds__(256) void fused_kernel(
        const float* __restrict__ src,   // stencil source buffer
        float* __restrict__ adst,        // destination: still-active samples
        float* __restrict__ fdst,        // destination: finishing samples (== out)
        const float* __restrict__ x,     // original input (t==0 copy, base==0)
        float* __restrict__ out,         // final output (t==0 copy dest)
        const int* __restrict__ t,
        const float* __restrict__ partials,
        const float* __restrict__ dcoef,
        int base) {
    const int b = blockIdx.y;
    const int tb = t[b];
    const int tx = blockIdx.x & 7;       // col tile 0..7
    const int ty = blockIdx.x >> 3;      // row tile 0..3
    const int h0 = ty * TSR;
    const int w0 = tx * TSC;

    if (tb <= base) {
        if (base == 0 && tb == 0) {
            // copy x -> out (clip applied; near-no-op on [0,1) input)
            const float4* s4 = (const float4*)(x + (size_t)b * HW);
            float4* d4 = (float4*)(out + (size_t)b * HW);
            for (int j = threadIdx.x; j < TSR * (TSC / 4); j += 256) {
                const int r = j >> 4, c4 = j & 15;
                const int idx = (h0 + r) * (WW / 4) + (w0 >> 2) + c4;
                d4[idx] = clamp4(s4[idx]);
            }
        }
        return;   // sample finished earlier; data already in out
    }

    int nst = tb - base;
    if (nst > NF) nst = NF;
    float* dstp = (tb <= base + NF) ? fdst : adst;

    // f computed inline (block-uniform, deterministic sequential sum)
    float psum = 0.f;
#pragma unroll
    for (int k = 0; k < RBLK; k++) psum += partials[b * RBLK + k];
    const float f = dcoef[0] * (1.0f / (1.0f + expf(-psum * (1.0f / (float)HW)))) * DT_C;

    __shared__ __align__(16) float pub[NSLOT][SLOTW];

    // ---- lane mapping: 6 strips x 10 col-groups per wave ----
    const int ln  = threadIdx.x & 63;
    const int si  = ln / 10;                 // 0..5 active, 6 = idle-duplicate
    const int g   = ln - si * 10;            // 8-col group 0..9 (0..3 for si=6)
    const bool act = (si < 6);
    const int s   = act ? ((threadIdx.x >> 6) * 6 + si) : 0;  // strip 0..23
    const int r1  = 1 + 6 * s;               // first owned local row
    const int cb  = 8 * (act ? g : 0);       // local col base 0..72

    const float* sb = src + (size_t)b * HW;
    const int gc = (w0 - 8 + cb) & (WW - 1); // global col base (8-aligned)

    // ---- load 6 rows x 8 cols straight into registers ----
    float4 cA[6], cB[6];
#pragma unroll
    for (int j = 0; j < 6; j++) {
        const int gr = (h0 - 9 + r1 + j) & (HH - 1);
        cA[j] = *(const float4*)(sb + gr * WW + gc);
        cB[j] = *(const float4*)(sb + gr * WW + gc + 4);
    }
    // static halo rows 0 and 145 -> slots 0 and NSLOT-1
    if (threadIdx.x < 40) {
        const int r  = threadIdx.x / 20;     // 0 or 1
        const int cg = threadIdx.x % 20;
        const int lr = r ? (ITR - 1) : 0;
        const int gr = (h0 - 9 + lr) & (HH - 1);
        const int gc4 = ((w0 >> 2) - 2 + cg) & (WW / 4 - 1);
        *(float4*)(&pub[r ? (NSLOT - 1) : 0][cg * 4]) =
            *(const float4*)(sb + gr * WW + gc4 * 4);
    }
    // initial publish of strip top/bottom
    if (act) {
        *(float4*)(&pub[2 * s + 1][cb])     = cA[0];
        *(float4*)(&pub[2 * s + 1][cb + 4]) = cB[0];
        *(float4*)(&pub[2 * s + 2][cb])     = cA[5];
        *(float4*)(&pub[2 * s + 2][cb + 4]) = cB[5];
    }
    __syncthreads();

    // ---- nst register-resident Euler steps (up-carry, in-place) ----
    for (int it = 0; it < nst; it++) {
        float4 uA = *(const float4*)(&pub[2 * s][cb]);
        float4 uB = *(const float4*)(&pub[2 * s][cb + 4]);
        const float4 dA = *(const float4*)(&pub[2 * s + 3][cb]);
        const float4 dB = *(const float4*)(&pub[2 * s + 3][cb + 4]);
#pragma unroll
        for (int j = 0; j < 6; j++) {
            const float4 a = cA[j];
            const float4 q = cB[j];
            const float4 nA = (j == 5) ? dA : cA[j + 1];
            const float4 nB = (j == 5) ? dB : cB[j + 1];
            const float L = __shfl_up(q.w, 1, 64);    // lane-1's col cb-1
            const float R = __shfl_down(a.x, 1, 64);  // lane+1's col cb+8
            float4 oA, oB;
            oA.x = fmaf(f, L   + a.y + uA.x + nA.x - 4.f * a.x, a.x);
            oA.y = fmaf(f, a.x + a.z + uA.y + nA.y - 4.f * a.y, a.y);
            oA.z = fmaf(f, a.y + a.w + uA.z + nA.z - 4.f * a.z, a.z);
            oA.w = fmaf(f, a.z + q.x + uA.w + nA.w - 4.f * a.w, a.w);
            oB.x = fmaf(f, a.w + q.y + uB.x + nB.x - 4.f * q.x, q.x);
            oB.y = fmaf(f, q.x + q.z + uB.y + nB.y - 4.f * q.y, q.y);
            oB.z = fmaf(f, q.y + q.w + uB.z + nB.z - 4.f * q.z, q.z);
            oB.w = fmaf(f, q.z + R   + uB.w + nB.w - 4.f * q.w, q.w);
            cA[j] = clamp4(oA);
            cB[j] = clamp4(oB);
            uA = a;
            uB = q;
        }
        __syncthreads();    // halo reads of this step complete
        if (act) {
            *(float4*)(&pub[2 * s + 1][cb])     = cA[0];
            *(float4*)(&pub[2 * s + 1][cb + 4]) = cB[0];
            *(float4*)(&pub[2 * s + 2][cb])     = cA[5];
            *(float4*)(&pub[2 * s + 2][cb + 4]) = cB[5];
        }
        __syncthreads();    // halo writes visible for next step
    }

    // ---- write output: local rows [9,137), cols [8,72) (groups 1..8) ----
    if (act && g >= 1 && g < 9) {
        float* db = dstp + (size_t)b * HW;
        const int gcol = w0 - 8 + cb;        // in [w0, w0+56]
#pragma unroll
        for (int j = 0; j < 6; j++) {
            const int lr = r1 + j;
            if (lr >= 9 && lr < 137) {
                float* p = db + (size_t)(h0 + lr - 9) * WW + gcol;
                *(float4*)p       = cA[j];
                *(float4*)(p + 4) = cB[j];
            }
        }
    }
}

extern "C" void kernel_launch(void* const* d_in, const int* in_sizes, int n_in,
                              void* d_out, int out_size, void* d_ws, size_t ws_size,
                              hipStream_t stream) {
    const float* x     = (const float*)d_in[0];
    const int*   t     = (const int*)d_in[1];
    const float* dcoef = (const float*)d_in[2];
    float* out = (float*)d_out;

    // ws layout (header 4 KiB): [partials: 32*16 floats][f1 @ 4 KiB: 32 MiB]
    float* partials = (float*)d_ws;
    float* f1       = (float*)((char*)d_ws + 4096);

    reduce_x_kernel<<<dim3(RBLK, BB), dim3(256), 0, stream>>>(x, t, partials);

    // Chain x -> f1 -> out; finishing samples always write out
    // (src never aliases out -> no hazard, no fix-up pass).
    fused_kernel<<<dim3(32, BB), dim3(256), 0, stream>>>(x,  f1, out, x, out, t, partials, dcoef, 0);
    fused_kernel<<<dim3(32, BB), dim3(256), 0, stream>>>(f1, f1, out, x, out, t, partials, dcoef, 8);
}